// Round 4
// baseline (618.173 us; speedup 1.0000x reference)
//
#include <hip/hip_runtime.h>
#include <math.h>

typedef __attribute__((ext_vector_type(8))) short short8;
typedef __attribute__((ext_vector_type(4))) float f32x4;

#define LRELU(x) ((x) > 0.0f ? (x) : 0.01f * (x))

__device__ __forceinline__ float bf2f(unsigned short h) {
    return __uint_as_float(((unsigned int)h) << 16);
}
__device__ __forceinline__ unsigned short f2bf(float f) {
    unsigned int u = __float_as_uint(f);
    return (unsigned short)((u + 0x7FFFu + ((u >> 16) & 1u)) >> 16);
}
__device__ __forceinline__ void gload_lds16(const void* g, void* l) {
    __builtin_amdgcn_global_load_lds(
        (const __attribute__((address_space(1))) unsigned int*)g,
        (__attribute__((address_space(3))) unsigned int*)l, 16, 0, 0);
}
__device__ __forceinline__ float2 stats_from(const float* sums, int b, float count) {
    float s = sums[2 * b], q = sums[2 * b + 1];
    float mean = s / count;
    float var = (q - s * s / count) / (count - 1.0f);  // ddof=1
    var = fmaxf(var, 0.0f);
    return make_float2(mean, 1.0f / (sqrtf(var) + 1e-5f));
}

// w [O][Cin][3] f32  ->  wq [O][3*Cin] bf16 with k' = j*Cin + c
__global__ void prep_weights(const float* __restrict__ w, unsigned short* __restrict__ wq,
                             int O, int Cin)
{
    const int K = 3 * Cin, total = O * K;
    for (int i = blockIdx.x * blockDim.x + threadIdx.x; i < total;
         i += gridDim.x * blockDim.x) {
        int o = i / K, kp = i - o * K;
        int j = kp / Cin, c = kp - j * Cin;
        wq[i] = f2bf(w[(o * Cin + c) * 3 + j]);
    }
}

// data slice [G][64][1024] f32 -> xT [G][1024][64] bf16.  blockIdx.x = local batch.
__global__ __launch_bounds__(256) void transpose_in(const float* __restrict__ in,
                                                    unsigned short* __restrict__ xT)
{
    const int b = blockIdx.x, n0 = blockIdx.y * 64;
    const float* inb = in + ((size_t)b * 64) * 1024;
    const int tid = threadIdx.x;
    __shared__ float tile[64][65];
    const int nn = tid & 63, cw = tid >> 6;
#pragma unroll
    for (int i = 0; i < 16; i++) {
        int c = i * 4 + cw;
        tile[c][nn] = inb[(size_t)c * 1024 + n0 + nn];
    }
    __syncthreads();
    const int n = tid >> 2, cp = (tid & 3) * 16;
    unsigned int pk[8];
#pragma unroll
    for (int i = 0; i < 8; i++) {
        unsigned short lo = f2bf(tile[cp + 2 * i][n]);
        unsigned short hi = f2bf(tile[cp + 2 * i + 1][n]);
        pk[i] = (unsigned int)lo | ((unsigned int)hi << 16);
    }
    unsigned short* dst = xT + ((size_t)b * 1024 + n0 + n) * 64 + cp;
    uint4 v0 = {pk[0], pk[1], pk[2], pk[3]};
    uint4 v1 = {pk[4], pk[5], pk[6], pk[7]};
    *(uint4*)dst = v0;
    *(uint4*)(dst + 8) = v1;
}

// MFMA gather-conv. blockIdx.x = local batch (XCD pin), .y = o-tile, .z = n-tile.
template <int BM>
__global__ __launch_bounds__(256) void conv_mfma(
    const unsigned short* __restrict__ xT,   // [G][1024][Cin] bf16
    const int* __restrict__ idx,             // [G][3069] (pre-offset for group)
    const unsigned short* __restrict__ wq,   // [O][K] bf16 (k'=j*Cin+c)
    const float* __restrict__ bias,          // [O] f32
    unsigned short* __restrict__ out,        // [G][1024][O] bf16
    float* __restrict__ sums,                // [G][2] accum
    int Cin, int cinShift, int O, int K)
{
    constexpr int WM = BM / 2, MT = WM / 16;
    const int b   = blockIdx.x;
    const int o0  = blockIdx.y * BM;
    const int nt0 = blockIdx.z << 7;
    const int tid = threadIdx.x;
    const int lane = tid & 63, wave = tid >> 6;
    const int wo = wave & 1, wn = wave >> 1;
    const int quad = lane >> 4, l15 = lane & 15;
    const int rl = (lane >> 3) & 7, blkid = lane & 7;
    const int swz = blkid ^ rl;   // logical 16B-block this lane stages

    __shared__ __align__(16) unsigned short wt[BM * 64];
    __shared__ __align__(16) unsigned short gt[128 * 64];

    f32x4 acc[MT][4];
#pragma unroll
    for (int i = 0; i < MT; i++)
#pragma unroll
        for (int t = 0; t < 4; t++) acc[i][t] = (f32x4){0.f, 0.f, 0.f, 0.f};

    const unsigned short* xTb = xT + (((size_t)b) << 10) * (size_t)Cin;
    const int* idxb = idx + (size_t)b * 3069;
    const int* ip[4];
#pragma unroll
    for (int p = 0; p < 4; p++) {
        int n = nt0 + p * 32 + wave * 8 + rl;
        int t = (n == 0) ? 0 : (n - 1);
        ip[p] = idxb + 3 * t;
    }

    const int nChunks = K >> 6;
    for (int kc = 0; kc < nChunks; ++kc) {
        const int k64 = kc << 6;
        const int j  = k64 >> cinShift;
        const int c0 = k64 & (Cin - 1);
#pragma unroll
        for (int p = 0; p < BM / 32; p++) {
            const int r0 = p * 32 + wave * 8;
            const int orow = o0 + r0 + rl;
            gload_lds16(wq + (size_t)orow * K + k64 + swz * 8, &wt[r0 * 64 + lane * 8]);
        }
#pragma unroll
        for (int p = 0; p < 4; p++) {
            const int s = ip[p][j];
            gload_lds16(xTb + (size_t)s * Cin + c0 + swz * 8,
                        &gt[(p * 32 + wave * 8) * 64 + lane * 8]);
        }
        __syncthreads();
#pragma unroll
        for (int st = 0; st < 2; ++st) {
            short8 af[MT], bfv[4];
            const int qb = st * 4 + quad;
#pragma unroll
            for (int i = 0; i < MT; i++) {
                const int orow = wo * WM + i * 16 + l15;
                af[i] = *(const short8*)&wt[orow * 64 + ((qb ^ blkid) << 3)];
            }
#pragma unroll
            for (int t = 0; t < 4; t++) {
                const int nrow = wn * 64 + t * 16 + l15;
                bfv[t] = *(const short8*)&gt[nrow * 64 + ((qb ^ blkid) << 3)];
            }
#pragma unroll
            for (int i = 0; i < MT; i++)
#pragma unroll
                for (int t = 0; t < 4; t++)
                    acc[i][t] = __builtin_amdgcn_mfma_f32_16x16x32_bf16(
                        af[i], bfv[t], acc[i][t], 0, 0, 0);
        }
        __syncthreads();
    }

    // epilogue: bias, zero col 0, bf16 store, fused stats
    float lsum = 0.f, lsq = 0.f;
#pragma unroll
    for (int i = 0; i < MT; i++) {
        const int ob = o0 + wo * WM + i * 16 + quad * 4;
        const float4 bv = *(const float4*)(bias + ob);
#pragma unroll
        for (int t = 0; t < 4; t++) {
            const int n = nt0 + wn * 64 + t * 16 + l15;
            float v0 = acc[i][t][0] + bv.x;
            float v1 = acc[i][t][1] + bv.y;
            float v2 = acc[i][t][2] + bv.z;
            float v3 = acc[i][t][3] + bv.w;
            if (n == 0) { v0 = v1 = v2 = v3 = 0.f; }
            lsum += v0 + v1 + v2 + v3;
            lsq  += v0 * v0 + v1 * v1 + v2 * v2 + v3 * v3;
            ushort4 pk;
            pk.x = f2bf(v0); pk.y = f2bf(v1); pk.z = f2bf(v2); pk.w = f2bf(v3);
            *(ushort4*)&out[((size_t)b * 1024 + n) * O + ob] = pk;
        }
    }
#pragma unroll
    for (int off = 32; off > 0; off >>= 1) {
        lsum += __shfl_down(lsum, off);
        lsq  += __shfl_down(lsq, off);
    }
    float* red = (float*)wt;  // wt dead after K-loop
    if (lane == 0) { red[wave] = lsum; red[4 + wave] = lsq; }
    __syncthreads();
    if (tid == 0) {
        atomicAdd(&sums[2 * b + 0], red[0] + red[1] + red[2] + red[3]);
        atomicAdd(&sums[2 * b + 1], red[4] + red[5] + red[6] + red[7]);
    }
}

// in-place: act = lrelu((act - mean) * inv).  blockIdx.x = local batch (XCD pin).
__global__ __launch_bounds__(256) void normalize_act(unsigned short* __restrict__ act,
                                                     const float* __restrict__ sums,
                                                     float count, int C)
{
    const int b = blockIdx.x;
    const float2 s = stats_from(sums, b, count);
    const float a = s.y, c2 = -s.x * s.y;
    size_t off = (((size_t)b << 10) * C) + ((size_t)blockIdx.y * 2048) + (size_t)threadIdx.x * 8;
    uint4* p = (uint4*)(act + off);
    uint4 v = *p;
    unsigned int w[4] = {v.x, v.y, v.z, v.w};
#pragma unroll
    for (int i = 0; i < 4; i++) {
        float lo = bf2f((unsigned short)(w[i] & 0xFFFFu));
        float hi = bf2f((unsigned short)(w[i] >> 16));
        lo = fmaf(lo, a, c2); lo = fmaxf(lo, 0.01f * lo);
        hi = fmaf(hi, a, c2); hi = fmaxf(hi, 0.01f * hi);
        w[i] = (unsigned int)f2bf(lo) | ((unsigned int)f2bf(hi) << 16);
    }
    uint4 r = {w[0], w[1], w[2], w[3]};
    *p = r;
}

// max over n (normalize pooled scalar: monotonic), fc1+lrelu, fc2
__global__ __launch_bounds__(256) void pool_fc(
    const unsigned short* __restrict__ act3,  // [G][1024][64] bf16
    const float* __restrict__ sums3, float count,
    const float* __restrict__ w_fc1, const float* __restrict__ b_fc1,
    const float* __restrict__ w_fc2, const float* __restrict__ b_fc2,
    float* __restrict__ y)
{
    const int b = blockIdx.x, tid = threadIdx.x;
    const int o = tid & 63, g = tid >> 6;
    const unsigned short* p = act3 + ((size_t)b * 1024 + g * 256) * 64 + o;
    float m = -1e30f;
#pragma unroll 8
    for (int i = 0; i < 256; i++) m = fmaxf(m, bf2f(p[(size_t)i * 64]));
    __shared__ float red[4][64];
    red[g][o] = m;
    __syncthreads();
    __shared__ float pooled[64];
    __shared__ float hid[32];
    if (tid < 64) {
        float mm = fmaxf(fmaxf(red[0][tid], red[1][tid]),
                         fmaxf(red[2][tid], red[3][tid]));
        float2 s = stats_from(sums3, b, count);
        pooled[tid] = (mm - s.x) * s.y;
    }
    __syncthreads();
    if (tid < 32) {
        float h = b_fc1[tid];
#pragma unroll
        for (int c = 0; c < 64; c++) h += pooled[c] * w_fc1[tid * 64 + c];
        hid[tid] = LRELU(h);
    }
    __syncthreads();
    if (tid == 0) {
        float v = b_fc2[0];
#pragma unroll
        for (int c = 0; c < 32; c++) v += hid[c] * w_fc2[c];
        y[b] = v;
    }
}

__global__ void sigmoid_diff(const float* __restrict__ y1,
                             const float* __restrict__ y2,
                             float* __restrict__ out)
{
    int b = threadIdx.x;
    if (b < 128) out[b] = 1.0f / (1.0f + expf(-(y1[b] - y2[b])));
}

extern "C" void kernel_launch(void* const* d_in, const int* in_sizes, int n_in,
                              void* d_out, int out_size, void* d_ws, size_t ws_size,
                              hipStream_t stream)
{
    const float* data1 = (const float*)d_in[0];
    const int*   idx1  = (const int*)d_in[1];
    const float* data2 = (const float*)d_in[2];
    const int*   idx2  = (const int*)d_in[3];
    const float* w1 = (const float*)d_in[4];
    const float* b1 = (const float*)d_in[5];
    const float* w2 = (const float*)d_in[6];
    const float* b2 = (const float*)d_in[7];
    const float* w3 = (const float*)d_in[8];
    const float* b3 = (const float*)d_in[9];
    const float* wfc1 = (const float*)d_in[10];
    const float* bfc1 = (const float*)d_in[11];
    const float* wfc2 = (const float*)d_in[12];
    const float* bfc2 = (const float*)d_in[13];

    // Depth-first batch groups: G=64 batches at a time so a1_group (33.5 MB)
    // stays L2-resident (8 slabs x 512 KB per XCD), gathers hit local L2.
    const int G = 64, NGROUPS = 4;
    const size_t szXT = (size_t)G * 1024 * 64 * 2;    // 8.4 MB (aliases a3)
    const size_t szA1 = (size_t)G * 1024 * 256 * 2;   // 33.5 MB
    const size_t szA2 = (size_t)G * 1024 * 128 * 2;   // 16.8 MB

    char* ws = (char*)d_ws;
    unsigned short* xT = (unsigned short*)ws;
    unsigned short* a1 = (unsigned short*)(ws + szXT);
    unsigned short* a2 = (unsigned short*)(ws + szXT + szA1);
    unsigned short* a3 = xT;                          // xT dead after conv1
    char* tail = ws + szXT + szA1 + szA2;
    unsigned short* wq1 = (unsigned short*)tail;                 // 96 KB
    unsigned short* wq2 = (unsigned short*)(tail + 128 * 1024);  // 192 KB
    unsigned short* wq3 = (unsigned short*)(tail + 384 * 1024);  // 48 KB
    float* sums = (float*)(tail + 448 * 1024);  // [NGROUPS][3][G][2] f32 = 6 KB
    float* yv   = (float*)(tail + 512 * 1024);  // 256 f32

    prep_weights<<<96, 256, 0, stream>>>(w1, wq1, 256, 64);
    prep_weights<<<96, 256, 0, stream>>>(w2, wq2, 128, 256);
    prep_weights<<<96, 256, 0, stream>>>(w3, wq3, 64, 128);
    hipMemsetAsync(sums, 0, NGROUPS * 3 * G * 2 * sizeof(float), stream);

    for (int g = 0; g < NGROUPS; ++g) {
        const float* data_g = (g < 2) ? data1 + (size_t)g * G * 64 * 1024
                                      : data2 + (size_t)(g - 2) * G * 64 * 1024;
        const int* idx_g = (g < 2) ? idx1 + (size_t)g * G * 3069
                                   : idx2 + (size_t)(g - 2) * G * 3069;
        float* s1 = sums + ((size_t)g * 3 + 0) * G * 2;
        float* s2 = sums + ((size_t)g * 3 + 1) * G * 2;
        float* s3 = sums + ((size_t)g * 3 + 2) * G * 2;

        transpose_in<<<dim3(G, 16), 256, 0, stream>>>(data_g, xT);

        conv_mfma<128><<<dim3(G, 2, 8), 256, 0, stream>>>(
            xT, idx_g, wq1, b1, a1, s1, 64, 6, 256, 192);
        normalize_act<<<dim3(G, 128), 256, 0, stream>>>(a1, s1, 256.0f * 1024.0f, 256);

        conv_mfma<128><<<dim3(G, 1, 8), 256, 0, stream>>>(
            a1, idx_g, wq2, b2, a2, s2, 256, 8, 128, 768);
        normalize_act<<<dim3(G, 64), 256, 0, stream>>>(a2, s2, 128.0f * 1024.0f, 128);

        conv_mfma<64><<<dim3(G, 1, 8), 256, 0, stream>>>(
            a2, idx_g, wq3, b3, a3, s3, 128, 7, 64, 384);

        pool_fc<<<G, 256, 0, stream>>>(a3, s3, 64.0f * 1024.0f,
                                       wfc1, bfc1, wfc2, bfc2, yv + g * G);
    }
    sigmoid_diff<<<1, 128, 0, stream>>>(yv, yv + 128, (float*)d_out);
}